// Round 17
// baseline (44.567 us; speedup 1.0000x reference)
//
#include <hip/hip_runtime.h>
#include <hip/hip_bf16.h>
#include <cstdint>
#include <cstddef>

// Problem constants
#define Bsz 16384
#define Esz 16
#define Ssz 64
#define Asz 32
#define Isz 96   // S + A
#define HSz 64
#define HRz 32

#define NTM 256       // 4 waves
#define SCHUNK 256    // state-block rows
#define SNTILE 4      // SCHUNK / (4 waves * 16 rows)
#define RCHUNK 512    // reward-block rows
#define RNTILE 8

typedef __attribute__((ext_vector_type(8))) short bf16x8;
typedef __attribute__((ext_vector_type(4))) short short4v;
typedef __attribute__((ext_vector_type(4))) float f32x4;

static __device__ __forceinline__ short f2bf(float f) {
    __hip_bfloat16 b = __float2bfloat16(f);   // pairs into v_cvt_pk_bf16_f32
    return *reinterpret_cast<short*>(&b);
}
static __device__ __forceinline__ float bf2f(short s) {
    union { uint32_t u; float f; } v; v.u = ((uint32_t)(uint16_t)s) << 16; return v.f;
}
static __device__ __forceinline__ bf16x8 pack8(float4 lo, float4 hi) {
    bf16x8 r;
    r[0] = f2bf(lo.x); r[1] = f2bf(lo.y); r[2] = f2bf(lo.z); r[3] = f2bf(lo.w);
    r[4] = f2bf(hi.x); r[5] = f2bf(hi.y); r[6] = f2bf(hi.z); r[7] = f2bf(hi.w);
    return r;
}

// ---- State kernel: LEAN (~163 VGPR demand) -> 3 waves/SIMD for real ----
// 1024 blocks (3 resident/CU + backfill). Weights W1/W2 only in VGPRs;
// swapped MFMA; XCD swizzle; HT transpose; OT full-line nt stores (R16 win).
__global__ __launch_bounds__(NTM, 3)
void state_mlp(const float* __restrict__ state, const float* __restrict__ action,
               const float* __restrict__ W1, const float* __restrict__ b1,
               const float* __restrict__ W2, const float* __restrict__ b2,
               float* __restrict__ outS)
{
    __shared__ __align__(16) short HT[4][16][68];    //  8704 B
    __shared__ __align__(16) float OT[4][16][72];    // 18432 B  (27136 total, 3 blocks/CU ok)

    // XCD swizzle over 1024 blocks: bid = xcd + 8*e + 128*chi (bijective)
    const int bid = blockIdx.x;
    const int xcd = bid & 7;
    const int e   = (bid >> 3) & (Esz - 1);
    const int chi = bid >> 7;                        // [0,8)
    const int c0  = (xcd + 8 * chi) * SCHUNK;

    const int w = threadIdx.x >> 6, lane = threadIdx.x & 63;
    const int lr = lane & 15, lg = lane >> 4;

    // Weight fragments: per-lane gather from f32 (proven R12 path)
    bf16x8 w1r[4][3], w2r[4][2];
    {
        const float* base = W1 + (size_t)e * Isz * HSz;
        #pragma unroll
        for (int nt = 0; nt < 4; ++nt)
            #pragma unroll
            for (int kk = 0; kk < 3; ++kk) {
                const float* p = base + (kk * 32 + lg * 8) * HSz + nt * 16 + lr;
                bf16x8 r;
                #pragma unroll
                for (int t = 0; t < 8; ++t) r[t] = f2bf(p[t * HSz]);
                w1r[nt][kk] = r;
            }
    }
    {
        const float* base = W2 + (size_t)e * HSz * Ssz;
        #pragma unroll
        for (int nt = 0; nt < 4; ++nt)
            #pragma unroll
            for (int kk = 0; kk < 2; ++kk) {
                const float* p = base + (kk * 32 + lg * 8) * Ssz + nt * 16 + lr;
                bf16x8 r;
                #pragma unroll
                for (int t = 0; t < 8; ++t) r[t] = f2bf(p[t * Ssz]);
                w2r[nt][kk] = r;
            }
    }
    // Biases packed bf16 (lane's D slots: n = nt*16 + lg*4 + j)
    short4v b1p[4], b2p[4];
    #pragma unroll
    for (int nt = 0; nt < 4; ++nt) {
        float4 v1 = *(const float4*)&b1[e * HSz + nt * 16 + lg * 4];
        float4 v2 = *(const float4*)&b2[e * Ssz + nt * 16 + lg * 4];
        b1p[nt] = (short4v){ f2bf(v1.x), f2bf(v1.y), f2bf(v1.z), f2bf(v1.w) };
        b2p[nt] = (short4v){ f2bf(v2.x), f2bf(v2.y), f2bf(v2.z), f2bf(v2.w) };
    }

    const int row0 = c0 + w * 16 + lr;               // lane's base batch row (m = lr)
    const float* sbase = state  + (size_t)row0 * Ssz + lg * 8;
    const float* abase = action + (size_t)row0 * Asz + lg * 8;

    float4 xs0 = *(const float4*)(sbase);
    float4 xs1 = *(const float4*)(sbase + 4);
    float4 xs2 = *(const float4*)(sbase + 32);
    float4 xs3 = *(const float4*)(sbase + 36);
    float4 xa0 = *(const float4*)(abase);
    float4 xa1 = *(const float4*)(abase + 4);
    bf16x8 a0 = pack8(xs0, xs1);
    bf16x8 a1 = pack8(xs2, xs3);
    bf16x8 a2 = pack8(xa0, xa1);

    #pragma unroll 1
    for (int t = 0; t < SNTILE; ++t) {
        const int tn = (t + 1) & (SNTILE - 1);       // wrap; last prefetch discarded
        const float* sp = sbase + (size_t)tn * 64 * Ssz;
        const float* ap = abase + (size_t)tn * 64 * Asz;
        float4 ns0 = *(const float4*)(sp);
        float4 ns1 = *(const float4*)(sp + 4);
        float4 ns2 = *(const float4*)(sp + 32);
        float4 ns3 = *(const float4*)(sp + 36);
        float4 na0 = *(const float4*)(ap);
        float4 na1 = *(const float4*)(ap + 4);

        // Layer 1
        f32x4 accS[4];
        #pragma unroll
        for (int nt = 0; nt < 4; ++nt) {
            f32x4 acc = (f32x4){ bf2f(b1p[nt][0]), bf2f(b1p[nt][1]),
                                 bf2f(b1p[nt][2]), bf2f(b1p[nt][3]) };
            acc = __builtin_amdgcn_mfma_f32_16x16x32_bf16(w1r[nt][0], a0, acc, 0, 0, 0);
            acc = __builtin_amdgcn_mfma_f32_16x16x32_bf16(w1r[nt][1], a1, acc, 0, 0, 0);
            acc = __builtin_amdgcn_mfma_f32_16x16x32_bf16(w1r[nt][2], a2, acc, 0, 0, 0);
            accS[nt] = acc;
        }
        // H = relu -> HT
        #pragma unroll
        for (int nt = 0; nt < 4; ++nt) {
            short4v p = { f2bf(fmaxf(accS[nt][0], 0.f)),
                          f2bf(fmaxf(accS[nt][1], 0.f)),
                          f2bf(fmaxf(accS[nt][2], 0.f)),
                          f2bf(fmaxf(accS[nt][3], 0.f)) };
            *(short4v*)&HT[w][lr][nt * 16 + lg * 4] = p;
        }
        // Layer 2 -> OT
        bf16x8 h0 = *(const bf16x8*)&HT[w][lr][lg * 8];
        bf16x8 h1 = *(const bf16x8*)&HT[w][lr][32 + lg * 8];
        #pragma unroll
        for (int nt = 0; nt < 4; ++nt) {
            f32x4 acc = (f32x4){ bf2f(b2p[nt][0]), bf2f(b2p[nt][1]),
                                 bf2f(b2p[nt][2]), bf2f(b2p[nt][3]) };
            acc = __builtin_amdgcn_mfma_f32_16x16x32_bf16(w2r[nt][0], h0, acc, 0, 0, 0);
            acc = __builtin_amdgcn_mfma_f32_16x16x32_bf16(w2r[nt][1], h1, acc, 0, 0, 0);
            *(f32x4*)&OT[w][lr][nt * 16 + lg * 4] = acc;
        }
        // Full-line coalesced nt stores: wave's 4 KB region as 4 x 1KB
        {
            const size_t obase = ((size_t)e * Bsz + c0 + t * 64 + w * 16) * Ssz;
            #pragma unroll
            for (int q = 0; q < 4; ++q) {
                f32x4 v = *(const f32x4*)&OT[w][4 * q + (lane >> 4)][(lane & 15) * 4];
                __builtin_nontemporal_store(v, (f32x4*)&outS[obase + q * 256 + lane * 4]);
            }
        }
        a0 = pack8(ns0, ns1);
        a1 = pack8(ns2, ns3);
        a2 = pack8(na0, na1);
    }
}

// ---- Reward kernel: light, 512 blocks, runs after state (X is L3-warm) ----
__global__ __launch_bounds__(NTM, 2)
void reward_mlp(const float* __restrict__ state, const float* __restrict__ action,
                const float* __restrict__ rW1, const float* __restrict__ rb1,
                const float* __restrict__ rW2, const float* __restrict__ rb2,
                float* __restrict__ outR)
{
    const int rbid = blockIdx.x;
    const int e  = rbid & (Esz - 1);
    const int c0 = (rbid >> 4) * RCHUNK;
    const int w = threadIdx.x >> 6, lane = threadIdx.x & 63;
    const int lr = lane & 15, lg = lane >> 4;

    bf16x8 rw1r[2][3];
    {
        const float* base = rW1 + (size_t)e * Isz * HRz;
        #pragma unroll
        for (int nt = 0; nt < 2; ++nt)
            #pragma unroll
            for (int kk = 0; kk < 3; ++kk) {
                const float* p = base + (kk * 32 + lg * 8) * HRz + nt * 16 + lr;
                bf16x8 r;
                #pragma unroll
                for (int t = 0; t < 8; ++t) r[t] = f2bf(p[t * HRz]);
                rw1r[nt][kk] = r;
            }
    }
    float4 rb1v[2], rw2v[2];
    #pragma unroll
    for (int nt = 0; nt < 2; ++nt) {
        rb1v[nt] = *(const float4*)&rb1[e * HRz + nt * 16 + lg * 4];
        rw2v[nt] = *(const float4*)&rW2[e * HRz + nt * 16 + lg * 4];
    }
    const float rb2s = rb2[e];

    const int row0 = c0 + w * 16 + lr;
    const float* sbase = state  + (size_t)row0 * Ssz + lg * 8;
    const float* abase = action + (size_t)row0 * Asz + lg * 8;

    #pragma unroll 1
    for (int t = 0; t < RNTILE; ++t) {
        const float* sp = sbase + (size_t)t * 64 * Ssz;
        const float* ap = abase + (size_t)t * 64 * Asz;
        bf16x8 a0 = pack8(*(const float4*)(sp),      *(const float4*)(sp + 4));
        bf16x8 a1 = pack8(*(const float4*)(sp + 32), *(const float4*)(sp + 36));
        bf16x8 a2 = pack8(*(const float4*)(ap),      *(const float4*)(ap + 4));

        f32x4 accR[2];
        #pragma unroll
        for (int nt = 0; nt < 2; ++nt) {
            f32x4 acc = (f32x4){ rb1v[nt].x, rb1v[nt].y, rb1v[nt].z, rb1v[nt].w };
            acc = __builtin_amdgcn_mfma_f32_16x16x32_bf16(rw1r[nt][0], a0, acc, 0, 0, 0);
            acc = __builtin_amdgcn_mfma_f32_16x16x32_bf16(rw1r[nt][1], a1, acc, 0, 0, 0);
            acc = __builtin_amdgcn_mfma_f32_16x16x32_bf16(rw1r[nt][2], a2, acc, 0, 0, 0);
            accR[nt] = acc;
        }
        float rp = 0.f;
        #pragma unroll
        for (int nt = 0; nt < 2; ++nt) {
            rp += fmaxf(accR[nt][0], 0.f) * rw2v[nt].x;
            rp += fmaxf(accR[nt][1], 0.f) * rw2v[nt].y;
            rp += fmaxf(accR[nt][2], 0.f) * rw2v[nt].z;
            rp += fmaxf(accR[nt][3], 0.f) * rw2v[nt].w;
        }
        rp += __shfl_xor(rp, 16);
        rp += __shfl_xor(rp, 32);
        if (lane < 16)
            __builtin_nontemporal_store(fminf(fmaxf(rp + rb2s, -100.f), 200.f),
                                        &outR[(size_t)e * Bsz + row0 + t * 64]);
    }
}

extern "C" void kernel_launch(void* const* d_in, const int* in_sizes, int n_in,
                              void* d_out, int out_size, void* d_ws, size_t ws_size,
                              hipStream_t stream) {
    const float* state  = (const float*)d_in[0];
    const float* action = (const float*)d_in[1];
    const float* W1  = (const float*)d_in[2];
    const float* b1  = (const float*)d_in[3];
    const float* W2  = (const float*)d_in[4];
    const float* b2  = (const float*)d_in[5];
    const float* rW1 = (const float*)d_in[6];
    const float* rb1 = (const float*)d_in[7];
    const float* rW2 = (const float*)d_in[8];
    const float* rb2 = (const float*)d_in[9];

    float* outS = (float*)d_out;                      // [E, B, S]
    float* outR = outS + (size_t)Esz * Bsz * Ssz;     // [E, B, 1]

    state_mlp<<<Esz * (Bsz / SCHUNK), NTM, 0, stream>>>(   // 1024 blocks
        state, action, W1, b1, W2, b2, outS);
    reward_mlp<<<Esz * (Bsz / RCHUNK), NTM, 0, stream>>>(  // 512 blocks
        state, action, rW1, rb1, rW2, rb2, outR);
}

// Round 18
// 44.140 us; speedup vs baseline: 1.0097x; 1.0097x over previous
//
#include <hip/hip_runtime.h>
#include <hip/hip_bf16.h>
#include <cstdint>
#include <cstddef>

// Problem constants
#define Bsz 16384
#define Esz 16
#define Ssz 64
#define Asz 32
#define Isz 96   // S + A
#define HSz 64
#define HRz 32

#define NTM 256       // 4 waves
#define NSB 1024      // state blocks
#define SCHUNK 256    // state rows per block
#define SNTILE 4
#define NRB 256       // reward blocks
#define RCHUNK 1024
#define RNTILE 16

typedef __attribute__((ext_vector_type(8))) short bf16x8;
typedef __attribute__((ext_vector_type(4))) short short4v;
typedef __attribute__((ext_vector_type(4))) float f32x4;

static __device__ __forceinline__ short f2bf(float f) {
    __hip_bfloat16 b = __float2bfloat16(f);   // pairs into v_cvt_pk_bf16_f32
    return *reinterpret_cast<short*>(&b);
}
static __device__ __forceinline__ float bf2f(short s) {
    union { uint32_t u; float f; } v; v.u = ((uint32_t)(uint16_t)s) << 16; return v.f;
}
static __device__ __forceinline__ bf16x8 pack8(float4 lo, float4 hi) {
    bf16x8 r;
    r[0] = f2bf(lo.x); r[1] = f2bf(lo.y); r[2] = f2bf(lo.z); r[3] = f2bf(lo.w);
    r[4] = f2bf(hi.x); r[5] = f2bf(hi.y); r[6] = f2bf(hi.z); r[7] = f2bf(hi.w);
    return r;
}

// Blocks [0,NSB): state MLP with weights in LDS (naturally low VGPR -> 3 waves/SIMD,
// 3 blocks/CU by LDS = 12 waves/CU). Blocks [NSB,NSB+NRB): reward MLP (light).
// NO waves/EU coercion (R5/R10/R15/R17 all proved forced bounds = spills).
// Swapped mfma(Wfrag, Xfrag): D lane: m = lane&15, n = nt*16 + (lane>>4)*4 + j.
// nt-stores + full-line OT stores (R16 win) + XCD sibling swizzle (R8 win).
__global__ __launch_bounds__(NTM)
void fused_all(const float* __restrict__ state, const float* __restrict__ action,
               const float* __restrict__ W1, const float* __restrict__ b1,
               const float* __restrict__ W2, const float* __restrict__ b2,
               const float* __restrict__ rW1, const float* __restrict__ rb1,
               const float* __restrict__ rW2, const float* __restrict__ rb2,
               float* __restrict__ outS, float* __restrict__ outR)
{
    // Transposed weights in LDS (read as b128 fragments per use, ~2-way banks)
    __shared__ __align__(16) short WT1[HSz][104];    // 13312 B  W1^T [h][i]
    __shared__ __align__(16) short WT2[Ssz][72];     //  9216 B  W2^T [s][h]
    __shared__ __align__(16) short HT[4][16][68];    //  8704 B  per-wave H transpose
    __shared__ __align__(16) float OT[4][16][72];    // 18432 B  per-wave output staging
    // total 49664 B -> 3 blocks/CU

    const int bid = blockIdx.x;
    const int tid = threadIdx.x;
    const int w = tid >> 6, lane = tid & 63;
    const int lr = lane & 15, lg = lane >> 4;

    if (bid < NSB) {
        // ================= STATE PATH =================
        // XCD swizzle (bijective over 1024): chunk = xcd + 8*chi, 16 e-siblings/XCD
        const int xcd = bid & 7;
        const int e   = (bid >> 3) & (Esz - 1);
        const int chi = bid >> 7;
        const int c0  = (xcd + 8 * chi) * SCHUNK;

        // ---- Cooperative staging: coalesced float4 loads -> bf16 transpose (R14) ----
        {   // W1 [i][h]: 1536 float4; float4 = 4 consecutive h at fixed i
            const float4* src = (const float4*)(W1 + (size_t)e * Isz * HSz);
            for (int q = tid; q < 1536; q += NTM) {
                float4 v = src[q];
                int i = q >> 4, h = (q & 15) * 4;
                WT1[h + 0][i] = f2bf(v.x);
                WT1[h + 1][i] = f2bf(v.y);
                WT1[h + 2][i] = f2bf(v.z);
                WT1[h + 3][i] = f2bf(v.w);
            }
        }
        {   // W2 [h][s]: 1024 float4; float4 = 4 consecutive s at fixed h
            const float4* src = (const float4*)(W2 + (size_t)e * HSz * Ssz);
            for (int q = tid; q < 1024; q += NTM) {
                float4 v = src[q];
                int h = q >> 4, s = (q & 15) * 4;
                WT2[s + 0][h] = f2bf(v.x);
                WT2[s + 1][h] = f2bf(v.y);
                WT2[s + 2][h] = f2bf(v.z);
                WT2[s + 3][h] = f2bf(v.w);
            }
        }
        // Biases packed bf16 (lane's D slots: n = nt*16 + lg*4 + j)
        short4v b1p[4], b2p[4];
        #pragma unroll
        for (int nt = 0; nt < 4; ++nt) {
            float4 v1 = *(const float4*)&b1[e * HSz + nt * 16 + lg * 4];
            float4 v2 = *(const float4*)&b2[e * Ssz + nt * 16 + lg * 4];
            b1p[nt] = (short4v){ f2bf(v1.x), f2bf(v1.y), f2bf(v1.z), f2bf(v1.w) };
            b2p[nt] = (short4v){ f2bf(v2.x), f2bf(v2.y), f2bf(v2.z), f2bf(v2.w) };
        }
        __syncthreads();   // weights staged (the only barrier)

        const int row0 = c0 + w * 16 + lr;
        const float* sbase = state  + (size_t)row0 * Ssz + lg * 8;
        const float* abase = action + (size_t)row0 * Asz + lg * 8;

        float4 xs0 = *(const float4*)(sbase);
        float4 xs1 = *(const float4*)(sbase + 4);
        float4 xs2 = *(const float4*)(sbase + 32);
        float4 xs3 = *(const float4*)(sbase + 36);
        float4 xa0 = *(const float4*)(abase);
        float4 xa1 = *(const float4*)(abase + 4);
        bf16x8 a0 = pack8(xs0, xs1);
        bf16x8 a1 = pack8(xs2, xs3);
        bf16x8 a2 = pack8(xa0, xa1);

        #pragma unroll 1
        for (int t = 0; t < SNTILE; ++t) {
            const int tn = (t + 1) & (SNTILE - 1);   // wrap; last prefetch discarded
            const float* sp = sbase + (size_t)tn * 64 * Ssz;
            const float* ap = abase + (size_t)tn * 64 * Asz;
            float4 ns0 = *(const float4*)(sp);
            float4 ns1 = *(const float4*)(sp + 4);
            float4 ns2 = *(const float4*)(sp + 32);
            float4 ns3 = *(const float4*)(sp + 36);
            float4 na0 = *(const float4*)(ap);
            float4 na1 = *(const float4*)(ap + 4);

            // Layer 1: fragments read from LDS per use (b128, ~2-way banks)
            f32x4 accS[4];
            #pragma unroll
            for (int nt = 0; nt < 4; ++nt) {
                f32x4 acc = (f32x4){ bf2f(b1p[nt][0]), bf2f(b1p[nt][1]),
                                     bf2f(b1p[nt][2]), bf2f(b1p[nt][3]) };
                acc = __builtin_amdgcn_mfma_f32_16x16x32_bf16(
                          *(const bf16x8*)&WT1[nt * 16 + lr][lg * 8],      a0, acc, 0, 0, 0);
                acc = __builtin_amdgcn_mfma_f32_16x16x32_bf16(
                          *(const bf16x8*)&WT1[nt * 16 + lr][32 + lg * 8], a1, acc, 0, 0, 0);
                acc = __builtin_amdgcn_mfma_f32_16x16x32_bf16(
                          *(const bf16x8*)&WT1[nt * 16 + lr][64 + lg * 8], a2, acc, 0, 0, 0);
                accS[nt] = acc;
            }
            // H = relu -> HT
            #pragma unroll
            for (int nt = 0; nt < 4; ++nt) {
                short4v p = { f2bf(fmaxf(accS[nt][0], 0.f)),
                              f2bf(fmaxf(accS[nt][1], 0.f)),
                              f2bf(fmaxf(accS[nt][2], 0.f)),
                              f2bf(fmaxf(accS[nt][3], 0.f)) };
                *(short4v*)&HT[w][lr][nt * 16 + lg * 4] = p;
            }
            // Layer 2 -> OT
            bf16x8 h0 = *(const bf16x8*)&HT[w][lr][lg * 8];
            bf16x8 h1 = *(const bf16x8*)&HT[w][lr][32 + lg * 8];
            #pragma unroll
            for (int nt = 0; nt < 4; ++nt) {
                f32x4 acc = (f32x4){ bf2f(b2p[nt][0]), bf2f(b2p[nt][1]),
                                     bf2f(b2p[nt][2]), bf2f(b2p[nt][3]) };
                acc = __builtin_amdgcn_mfma_f32_16x16x32_bf16(
                          *(const bf16x8*)&WT2[nt * 16 + lr][lg * 8],      h0, acc, 0, 0, 0);
                acc = __builtin_amdgcn_mfma_f32_16x16x32_bf16(
                          *(const bf16x8*)&WT2[nt * 16 + lr][32 + lg * 8], h1, acc, 0, 0, 0);
                *(f32x4*)&OT[w][lr][nt * 16 + lg * 4] = acc;
            }
            // Full-line coalesced nt stores: wave's 4 KB region as 4 x 1KB
            {
                const size_t obase = ((size_t)e * Bsz + c0 + t * 64 + w * 16) * Ssz;
                #pragma unroll
                for (int q = 0; q < 4; ++q) {
                    f32x4 v = *(const f32x4*)&OT[w][4 * q + (lane >> 4)][(lane & 15) * 4];
                    __builtin_nontemporal_store(v, (f32x4*)&outS[obase + q * 256 + lane * 4]);
                }
            }
            a0 = pack8(ns0, ns1);
            a1 = pack8(ns2, ns3);
            a2 = pack8(na0, na1);
        }
    } else {
        // ================= REWARD PATH (weights in VGPR, light) =================
        const int rbid = bid - NSB;
        const int e  = rbid & (Esz - 1);
        const int c0 = (rbid >> 4) * RCHUNK;

        bf16x8 rw1r[2][3];
        {
            const float* base = rW1 + (size_t)e * Isz * HRz;
            #pragma unroll
            for (int nt = 0; nt < 2; ++nt)
                #pragma unroll
                for (int kk = 0; kk < 3; ++kk) {
                    const float* p = base + (kk * 32 + lg * 8) * HRz + nt * 16 + lr;
                    bf16x8 r;
                    #pragma unroll
                    for (int t = 0; t < 8; ++t) r[t] = f2bf(p[t * HRz]);
                    rw1r[nt][kk] = r;
                }
        }
        float4 rb1v[2], rw2v[2];
        #pragma unroll
        for (int nt = 0; nt < 2; ++nt) {
            rb1v[nt] = *(const float4*)&rb1[e * HRz + nt * 16 + lg * 4];
            rw2v[nt] = *(const float4*)&rW2[e * HRz + nt * 16 + lg * 4];
        }
        const float rb2s = rb2[e];

        const int row0 = c0 + w * 16 + lr;
        const float* sbase = state  + (size_t)row0 * Ssz + lg * 8;
        const float* abase = action + (size_t)row0 * Asz + lg * 8;

        float4 xs0 = *(const float4*)(sbase);
        float4 xs1 = *(const float4*)(sbase + 4);
        float4 xs2 = *(const float4*)(sbase + 32);
        float4 xs3 = *(const float4*)(sbase + 36);
        float4 xa0 = *(const float4*)(abase);
        float4 xa1 = *(const float4*)(abase + 4);
        bf16x8 a0 = pack8(xs0, xs1);
        bf16x8 a1 = pack8(xs2, xs3);
        bf16x8 a2 = pack8(xa0, xa1);

        #pragma unroll 1
        for (int t = 0; t < RNTILE; ++t) {
            const int tn = (t + 1) & (RNTILE - 1);
            const float* sp = sbase + (size_t)tn * 64 * Ssz;
            const float* ap = abase + (size_t)tn * 64 * Asz;
            float4 ns0 = *(const float4*)(sp);
            float4 ns1 = *(const float4*)(sp + 4);
            float4 ns2 = *(const float4*)(sp + 32);
            float4 ns3 = *(const float4*)(sp + 36);
            float4 na0 = *(const float4*)(ap);
            float4 na1 = *(const float4*)(ap + 4);

            f32x4 accR[2];
            #pragma unroll
            for (int nt = 0; nt < 2; ++nt) {
                f32x4 acc = (f32x4){ rb1v[nt].x, rb1v[nt].y, rb1v[nt].z, rb1v[nt].w };
                acc = __builtin_amdgcn_mfma_f32_16x16x32_bf16(rw1r[nt][0], a0, acc, 0, 0, 0);
                acc = __builtin_amdgcn_mfma_f32_16x16x32_bf16(rw1r[nt][1], a1, acc, 0, 0, 0);
                acc = __builtin_amdgcn_mfma_f32_16x16x32_bf16(rw1r[nt][2], a2, acc, 0, 0, 0);
                accR[nt] = acc;
            }
            float rp = 0.f;
            #pragma unroll
            for (int nt = 0; nt < 2; ++nt) {
                rp += fmaxf(accR[nt][0], 0.f) * rw2v[nt].x;
                rp += fmaxf(accR[nt][1], 0.f) * rw2v[nt].y;
                rp += fmaxf(accR[nt][2], 0.f) * rw2v[nt].z;
                rp += fmaxf(accR[nt][3], 0.f) * rw2v[nt].w;
            }
            rp += __shfl_xor(rp, 16);
            rp += __shfl_xor(rp, 32);
            if (lane < 16)
                __builtin_nontemporal_store(fminf(fmaxf(rp + rb2s, -100.f), 200.f),
                                            &outR[(size_t)e * Bsz + row0 + t * 64]);
            a0 = pack8(ns0, ns1);
            a1 = pack8(ns2, ns3);
            a2 = pack8(na0, na1);
        }
    }
}

extern "C" void kernel_launch(void* const* d_in, const int* in_sizes, int n_in,
                              void* d_out, int out_size, void* d_ws, size_t ws_size,
                              hipStream_t stream) {
    const float* state  = (const float*)d_in[0];
    const float* action = (const float*)d_in[1];
    const float* W1  = (const float*)d_in[2];
    const float* b1  = (const float*)d_in[3];
    const float* W2  = (const float*)d_in[4];
    const float* b2  = (const float*)d_in[5];
    const float* rW1 = (const float*)d_in[6];
    const float* rb1 = (const float*)d_in[7];
    const float* rW2 = (const float*)d_in[8];
    const float* rb2 = (const float*)d_in[9];

    float* outS = (float*)d_out;                      // [E, B, S]
    float* outR = outS + (size_t)Esz * Bsz * Ssz;     // [E, B, 1]

    fused_all<<<NSB + NRB, NTM, 0, stream>>>(         // 1280 blocks
        state, action, W1, b1, W2, b2, rW1, rb1, rW2, rb2, outS, outR);
}